// Round 13
// baseline (181.734 us; speedup 1.0000x reference)
//
#include <hip/hip_runtime.h>
#include <math.h>
#include <stdint.h>

typedef __attribute__((ext_vector_type(8))) __bf16 bf16x8;
typedef __attribute__((ext_vector_type(16))) float f32x16;

#define Z16 {0.f,0.f,0.f,0.f,0.f,0.f,0.f,0.f,0.f,0.f,0.f,0.f,0.f,0.f,0.f,0.f}

__device__ __forceinline__ unsigned short f2b(float f) {
  union { float f; uint32_t u; } v; v.f = f;
  uint32_t r = (v.u + 0x7FFFu + ((v.u >> 16) & 1u)) >> 16;
  return (unsigned short)r;
}
__device__ __forceinline__ float b2f(unsigned short u) {
  union { uint32_t u; float f; } v; v.u = ((uint32_t)u) << 16;
  return v.f;
}
__device__ __forceinline__ uint32_t pk2(float a, float b) {
  return (uint32_t)f2b(a) | ((uint32_t)f2b(b) << 16);
}
__device__ __forceinline__ uint32_t cvtpk(float lo, float hi) {
  uint32_t r;
  asm("v_cvt_pk_bf16_f32 %0, %1, %2" : "=v"(r) : "v"(lo), "v"(hi));
  return r;
}
__device__ __forceinline__ void glds16(const void* g, void* l) {
  __builtin_amdgcn_global_load_lds(
      (const __attribute__((address_space(1))) void*)g,
      (__attribute__((address_space(3))) void*)l, 16, 0, 0);
}
#define MFMA32(a, b, c) __builtin_amdgcn_mfma_f32_32x32x16_bf16(a, b, c, 0, 0, 0)

union U8 { uint4 u; unsigned short s[8]; };

// ===================== fused preprocessing =====================
__global__ __launch_bounds__(256) void prep(
    const float* __restrict__ q, const float* __restrict__ x,
    unsigned short* __restrict__ qh, unsigned short* __restrict__ xh,
    const float* __restrict__ Wq, const float* __restrict__ Wk,
    const float* __restrict__ Wv, const float* __restrict__ Wo,
    const float* __restrict__ Wm, const float* __restrict__ We,
    unsigned short* __restrict__ WqT, unsigned short* __restrict__ WkvT,
    unsigned short* __restrict__ WoT, unsigned short* __restrict__ WmT,
    unsigned short* __restrict__ WeT,
    const float* __restrict__ bk, const float* __restrict__ bv,
    float* __restrict__ bkv) {
  __shared__ float T[64][68];
  const int bx = blockIdx.x, tid = threadIdx.x;
  if (bx < 2048) {
    const float* src = (bx < 1024) ? q : x;
    unsigned short* dst = (bx < 1024) ? qh : xh;
    const int i = (bx & 1023) * 256 + tid;
    float4 a = ((const float4*)src)[i * 2];
    float4 b = ((const float4*)src)[i * 2 + 1];
    uint4 o;
    o.x = cvtpk(a.x, a.y); o.y = cvtpk(a.z, a.w);
    o.z = cvtpk(b.x, b.y); o.w = cvtpk(b.z, b.w);
    ((uint4*)dst)[i] = o;
  } else if (bx < 2240) {
    int t = bx - 2048;
    const float* in; unsigned short* out; int ldin, ldout, kx, nx;
    if (t < 16)       { in = Wq; out = WqT;           ldin = 256;  ldout = 256;  kx = t & 3;  nx = t >> 2; }
    else if (t < 32)  { t -= 16;  in = Wk; out = WkvT;          ldin = 256;  ldout = 256;  kx = t & 3;  nx = t >> 2; }
    else if (t < 48)  { t -= 32;  in = Wv; out = WkvT + 65536;  ldin = 256;  ldout = 256;  kx = t & 3;  nx = t >> 2; }
    else if (t < 64)  { t -= 48;  in = Wo; out = WoT;           ldin = 256;  ldout = 256;  kx = t & 3;  nx = t >> 2; }
    else if (t < 128) { t -= 64;  in = Wm; out = WmT;           ldin = 1024; ldout = 256;  kx = t & 3;  nx = t >> 2; }
    else              { t -= 128; in = We; out = WeT;           ldin = 256;  ldout = 1024; kx = t & 15; nx = t >> 4; }
    const int k0 = kx * 64, n0 = nx * 64;
    const int r = tid >> 2, c16 = (tid & 3) * 16;
    #pragma unroll
    for (int i = 0; i < 4; ++i)
      *(float4*)&T[r][c16 + i * 4] =
          *(const float4*)&in[(size_t)(k0 + r) * ldin + n0 + c16 + i * 4];
    __syncthreads();
    const int n = tid >> 2, k16 = (tid & 3) * 16;
    uint32_t wb[8];
    #pragma unroll
    for (int p = 0; p < 8; ++p)
      wb[p] = cvtpk(T[k16 + 2 * p][n], T[k16 + 2 * p + 1][n]);
    uint4 o0, o1;
    o0.x = wb[0]; o0.y = wb[1]; o0.z = wb[2]; o0.w = wb[3];
    o1.x = wb[4]; o1.y = wb[5]; o1.z = wb[6]; o1.w = wb[7];
    *(uint4*)&out[(size_t)(n0 + n) * ldout + k0 + k16] = o0;
    *(uint4*)&out[(size_t)(n0 + n) * ldout + k0 + k16 + 8] = o1;
  } else {
    if (tid < 256) { bkv[tid] = bk[tid]; bkv[256 + tid] = bv[tid]; }
  }
}

// ===================== fused projections: Q + KV, 128x64 tile, BK=64, dbuf =====================
__global__ __launch_bounds__(256, 2) void gemm_proj(
    const unsigned short* __restrict__ qh, const unsigned short* __restrict__ xh,
    const unsigned short* __restrict__ WqT, const unsigned short* __restrict__ WkvT,
    const float* __restrict__ bq, const float* __restrict__ bkv,
    unsigned short* __restrict__ Qb, unsigned short* __restrict__ Kb,
    unsigned short* __restrict__ Vt) {
  __shared__ __align__(16) unsigned short As[2 * 128 * 64];
  __shared__ __align__(16) unsigned short Bs[2 * 64 * 64];
  const int tid = threadIdx.x, lane = tid & 63, wid = tid >> 6;
  const int l31 = lane & 31, g2 = lane >> 5;
  const bool qmode = blockIdx.y < 4;
  const int m0 = blockIdx.x * 128;
  const int n0 = qmode ? blockIdx.y * 64 : (blockIdx.y - 4) * 64;
  const unsigned short* A = qmode ? qh : xh;
  const unsigned short* Bt = qmode ? WqT : WkvT;
  const float* bias = qmode ? bq : bkv;

  const char* srcA[4];
  const char* srcB[2];
  #pragma unroll
  for (int p = 0; p < 4; ++p) {
    int row = p * 32 + wid * 8 + (lane >> 3);
    srcA[p] = (const char*)A + ((size_t)(m0 + row) * 256) * 2 + (lane & 7) * 16;
  }
  #pragma unroll
  for (int p = 0; p < 2; ++p) {
    int row = p * 32 + wid * 8 + (lane >> 3);
    srcB[p] = (const char*)Bt + ((size_t)(n0 + row) * 256) * 2 + (lane & 7) * 16;
  }

  f32x16 acc0 = Z16, acc1 = Z16;

  #pragma unroll
  for (int p = 0; p < 4; ++p) { glds16(srcA[p], &As[p * 2048 + wid * 512]); srcA[p] += 128; }
  #pragma unroll
  for (int p = 0; p < 2; ++p) { glds16(srcB[p], &Bs[p * 2048 + wid * 512]); srcB[p] += 128; }
  __syncthreads();

  for (int t = 0; t < 4; ++t) {
    const int cur = t & 1, nxt = cur ^ 1;
    if (t + 1 < 4) {
      #pragma unroll
      for (int p = 0; p < 4; ++p) { glds16(srcA[p], &As[nxt * 8192 + p * 2048 + wid * 512]); srcA[p] += 128; }
      #pragma unroll
      for (int p = 0; p < 2; ++p) { glds16(srcB[p], &Bs[nxt * 4096 + p * 2048 + wid * 512]); srcB[p] += 128; }
    }
    const char* as = (const char*)As + cur * 16384;
    const char* bs = (const char*)Bs + cur * 8192;
    #pragma unroll
    for (int kc = 0; kc < 4; ++kc) {
      const int xo = kc * 32 + g2 * 16;
      bf16x8 af  = *(const bf16x8*)(as + (wid * 32 + l31) * 128 + xo);
      bf16x8 b0v = *(const bf16x8*)(bs + l31 * 128 + xo);
      bf16x8 b1v = *(const bf16x8*)(bs + (32 + l31) * 128 + xo);
      acc0 = MFMA32(af, b0v, acc0);
      acc1 = MFMA32(af, b1v, acc1);
    }
    __syncthreads();
  }

  const int bb = m0 >> 11;
  #pragma unroll
  for (int nb = 0; nb < 2; ++nb) {
    const f32x16& acc = nb ? acc1 : acc0;
    const int col = n0 + nb * 32 + l31;
    const float bs = bias[col];
    if (qmode) {
      #pragma unroll
      for (int r = 0; r < 16; ++r) {
        const int m = m0 + wid * 32 + (r & 3) + 8 * (r >> 2) + 4 * g2;
        Qb[(size_t)m * 256 + col] = f2b(acc[r] + bs);
      }
    } else if (n0 < 256) {
      #pragma unroll
      for (int r = 0; r < 16; ++r) {
        const int m = m0 + wid * 32 + (r & 3) + 8 * (r >> 2) + 4 * g2;
        Kb[(size_t)m * 256 + col] = f2b(acc[r] + bs);
      }
    } else {
      const int hv = (col - 256) >> 5, dv = (col - 256) & 31;
      unsigned short* vrow = Vt + ((size_t)(bb * 8 + hv) * 32 + dv) * 2048;
      #pragma unroll
      for (int tq = 0; tq < 4; ++tq) {
        const int ks = (m0 & 2047) + wid * 32 + 8 * tq + 4 * g2;
        uint2 wv;
        wv.x = pk2(acc[4 * tq + 0] + bs, acc[4 * tq + 1] + bs);
        wv.y = pk2(acc[4 * tq + 2] + bs, acc[4 * tq + 3] + bs);
        *(uint2*)(vrow + ks) = wv;
      }
    }
  }
}

// ===================== GEMM small: 64x64 tile, BK=64, dbuf (EPI 3 used for We) =====================
template <int EPI>
__global__ __launch_bounds__(256, 2) void gemm_small(
    const unsigned short* __restrict__ A, int lda,
    const unsigned short* __restrict__ Bt, int ldb,
    const float* __restrict__ bias,
    const unsigned short* __restrict__ res, int ldr,
    void* __restrict__ Cout, int ldc, int K) {
  __shared__ __align__(16) unsigned short As[2 * 64 * 64];
  __shared__ __align__(16) unsigned short Bs[2 * 64 * 64];
  const int tid = threadIdx.x, lane = tid & 63, wid = tid >> 6;
  const int l31 = lane & 31, g2 = lane >> 5;
  const int m0 = blockIdx.x * 64, n0 = blockIdx.y * 64;
  const int wr = (wid >> 1) * 32, wc = (wid & 1) * 32;

  const char* srcA[2];
  const char* srcB[2];
  #pragma unroll
  for (int p = 0; p < 2; ++p) {
    int row = p * 32 + wid * 8 + (lane >> 3);
    srcA[p] = (const char*)A + ((size_t)(m0 + row) * lda) * 2 + (lane & 7) * 16;
    srcB[p] = (const char*)Bt + ((size_t)(n0 + row) * ldb) * 2 + (lane & 7) * 16;
  }

  f32x16 acc = Z16;
  const int nt = K >> 6;

  #pragma unroll
  for (int p = 0; p < 2; ++p) {
    glds16(srcA[p], &As[p * 2048 + wid * 512]); srcA[p] += 128;
    glds16(srcB[p], &Bs[p * 2048 + wid * 512]); srcB[p] += 128;
  }
  __syncthreads();

  for (int t = 0; t < nt; ++t) {
    const int cur = t & 1, nxt = cur ^ 1;
    if (t + 1 < nt) {
      #pragma unroll
      for (int p = 0; p < 2; ++p) {
        glds16(srcA[p], &As[nxt * 4096 + p * 2048 + wid * 512]); srcA[p] += 128;
        glds16(srcB[p], &Bs[nxt * 4096 + p * 2048 + wid * 512]); srcB[p] += 128;
      }
    }
    const char* as = (const char*)As + cur * 8192;
    const char* bs = (const char*)Bs + cur * 8192;
    #pragma unroll
    for (int kc = 0; kc < 4; ++kc) {
      const int xo = kc * 32 + g2 * 16;
      bf16x8 af = *(const bf16x8*)(as + (wr + l31) * 128 + xo);
      bf16x8 bf = *(const bf16x8*)(bs + (wc + l31) * 128 + xo);
      acc = MFMA32(af, bf, acc);
    }
    __syncthreads();
  }

  const int col = n0 + wc + l31;
  const float bs = bias[col];
  #pragma unroll
  for (int r = 0; r < 16; ++r) {
    const int m = m0 + wr + (r & 3) + 8 * (r >> 2) + 4 * g2;
    float v = acc[r] + bs;
    if (EPI == 1) v = fmaxf(v, 0.f);
    if (EPI == 1 || EPI == 3) v += b2f(res[(size_t)m * ldr + col]);
    if (EPI == 3)
      ((float*)Cout)[(size_t)m * ldc + col] = v;
    else
      ((unsigned short*)Cout)[(size_t)m * ldc + col] = f2b(v);
  }
}

// ===================== attention v6: kv-split x4, KVBLK=128, no-max softmax =====================
#define KLD 40
#define VLD2 136
__global__ __launch_bounds__(256, 4) void attn6(
    const unsigned short* __restrict__ Qg,
    const unsigned short* __restrict__ Kb,
    const unsigned short* __restrict__ Vt,
    unsigned short* __restrict__ Op0, unsigned short* __restrict__ Op1,
    unsigned short* __restrict__ Op2, unsigned short* __restrict__ Op3,
    unsigned short* __restrict__ lp) {
  __shared__ __align__(16) unsigned short Ks[128 * KLD];
  __shared__ __align__(16) unsigned short Vs[32 * VLD2];
  const int tid = threadIdx.x, lane = tid & 63, wid = tid >> 6;
  const int l31 = lane & 31, g2 = lane >> 5;
  const int w = (blockIdx.x >> 3) + (blockIdx.x & 7) * 256;
  const int b = w >> 9, h = (w >> 6) & 7, kv = (w >> 4) & 3, qt = w & 15;
  const int row0 = b * 2048 + qt * 128;
  const int qrow = row0 + wid * 32 + l31;
  const int kt0 = kv * 512;

  const float SCL2 = 0.17677669529663687f * 1.4426950408889634f;
  bf16x8 qf0, qf1;
  {
    const unsigned short* qp = Qg + (size_t)qrow * 256 + h * 32 + g2 * 8;
    #pragma unroll
    for (int dc = 0; dc < 2; ++dc) {
      ushort4 r0 = *(const ushort4*)(qp + dc * 16);
      ushort4 r1 = *(const ushort4*)(qp + dc * 16 + 4);
      union { unsigned short s[8]; bf16x8 v; } u;
      u.s[0] = f2b(b2f(r0.x) * SCL2); u.s[1] = f2b(b2f(r0.y) * SCL2);
      u.s[2] = f2b(b2f(r0.z) * SCL2); u.s[3] = f2b(b2f(r0.w) * SCL2);
      u.s[4] = f2b(b2f(r1.x) * SCL2); u.s[5] = f2b(b2f(r1.y) * SCL2);
      u.s[6] = f2b(b2f(r1.z) * SCL2); u.s[7] = f2b(b2f(r1.w) * SCL2);
      if (dc == 0) qf0 = u.v; else qf1 = u.v;
    }
  }

  const int ksr = tid >> 2, ksc = (tid & 3) * 8;
  const unsigned short* srcK = Kb + (size_t)(b * 2048 + kt0 + ksr) * 256 + h * 32 + ksc;
  const int vd = tid >> 3, vk = (tid & 7) * 8;
  const unsigned short* srcV = Vt + ((size_t)((b * 8 + h) * 32 + vd)) * 2048 + kt0 + vk;

  uint4 kreg0 = *(const uint4*)srcK;
  uint4 kreg1 = *(const uint4*)(srcK + 64 * 256);
  uint4 vreg0 = *(const uint4*)srcV;
  uint4 vreg1 = *(const uint4*)(srcV + 64);

  f32x16 oacc = Z16;
  float lr0 = 0.f, lr1 = 0.f;

  for (int kt = 0; kt < 512; kt += 128) {
    *(uint4*)&Ks[ksr * KLD + ksc] = kreg0;
    *(uint4*)&Ks[(64 + ksr) * KLD + ksc] = kreg1;
    *(uint4*)&Vs[vd * VLD2 + vk] = vreg0;
    *(uint4*)&Vs[vd * VLD2 + 64 + vk] = vreg1;
    __syncthreads();

    if (kt + 128 < 512) {
      srcK += 128 * 256;
      kreg0 = *(const uint4*)srcK;
      kreg1 = *(const uint4*)(srcK + 64 * 256);
      srcV += 128;
      vreg0 = *(const uint4*)srcV;
      vreg1 = *(const uint4*)(srcV + 64);
    }

    #pragma unroll
    for (int st = 0; st < 2; ++st) {
      const int kb0 = st * 64;
      f32x16 p0 = Z16, p1 = Z16;
      {
        bf16x8 k00 = *(const bf16x8*)&Ks[(kb0 + l31) * KLD + g2 * 8];
        bf16x8 k01 = *(const bf16x8*)&Ks[(kb0 + l31) * KLD + 16 + g2 * 8];
        bf16x8 k10 = *(const bf16x8*)&Ks[(kb0 + 32 + l31) * KLD + g2 * 8];
        bf16x8 k11 = *(const bf16x8*)&Ks[(kb0 + 32 + l31) * KLD + 16 + g2 * 8];
        p0 = MFMA32(k00, qf0, p0);
        p0 = MFMA32(k01, qf1, p0);
        p1 = MFMA32(k10, qf0, p1);
        p1 = MFMA32(k11, qf1, p1);
      }

      float s0 = 0.f, s1 = 0.f;
      #pragma unroll
      for (int i = 0; i < 16; ++i) { p0[i] = __builtin_amdgcn_exp2f(p0[i]); s0 += p0[i]; }
      #pragma unroll
      for (int i = 0; i < 16; ++i) { p1[i] = __builtin_amdgcn_exp2f(p1[i]); s1 += p1[i]; }
      lr0 += s0; lr1 += s1;

      #pragma unroll
      for (int rb = 0; rb < 2; ++rb) {
        const f32x16& pp = rb ? p1 : p0;
        #pragma unroll
        for (int c = 0; c < 2; ++c) {
          uint32_t A0 = cvtpk(pp[8 * c + 0], pp[8 * c + 1]);
          uint32_t A1 = cvtpk(pp[8 * c + 2], pp[8 * c + 3]);
          uint32_t B0 = cvtpk(pp[8 * c + 4], pp[8 * c + 5]);
          uint32_t B1 = cvtpk(pp[8 * c + 6], pp[8 * c + 7]);
          uint32_t pA0 = (uint32_t)__shfl_xor((int)A0, 32);
          uint32_t pB0 = (uint32_t)__shfl_xor((int)B0, 32);
          uint32_t pA1 = (uint32_t)__shfl_xor((int)A1, 32);
          uint32_t pB1 = (uint32_t)__shfl_xor((int)B1, 32);
          union { uint32_t u[4]; bf16x8 v; } fr;
          fr.u[0] = g2 ? pB0 : A0;
          fr.u[1] = g2 ? pB1 : A1;
          fr.u[2] = g2 ? B0 : pA0;
          fr.u[3] = g2 ? B1 : pA1;
          bf16x8 vf = *(const bf16x8*)&Vs[l31 * VLD2 + kb0 + rb * 32 + c * 16 + g2 * 8];
          oacc = MFMA32(vf, fr.v, oacc);
        }
      }
    }
    __syncthreads();
  }

  float lrun = lr0 + lr1;
  lrun += __shfl_xor(lrun, 32);
  unsigned short* op =
      (kv == 0 ? Op0 : kv == 1 ? Op1 : kv == 2 ? Op2 : Op3) +
      (size_t)qrow * 256 + h * 32;
  #pragma unroll
  for (int j = 0; j < 4; ++j) {
    uint2 wv;
    wv.x = cvtpk(oacc[4 * j + 0], oacc[4 * j + 1]);
    wv.y = cvtpk(oacc[4 * j + 2], oacc[4 * j + 3]);
    *(uint2*)(op + 8 * j + 4 * g2) = wv;
  }
  if (g2 == 0)
    lp[(((size_t)kv * 4 + b) * 8 + h) * 2048 + (qt * 128 + wid * 32 + l31)] = f2b(lrun);
}

// ===================== wo_fused: combine + LN0 + Wo GEMM + relu + residual =====================
// grid (4, 128): 64x64 tiles. A = LN0(Q + sum(Op)/sum(l)) staged in LDS; B fully staged.
// Zero-barrier K-loop (16 MFMA straight). Residual read from LDS.
#define ALD 264   // padded row stride (shorts): 528B, 16B-aligned, ~4-way banks
__global__ __launch_bounds__(256, 2) void wo_fused(
    const unsigned short* __restrict__ Op0, const unsigned short* __restrict__ Op1,
    const unsigned short* __restrict__ Op2, const unsigned short* __restrict__ Op3,
    const unsigned short* __restrict__ lp, const unsigned short* __restrict__ Qb,
    const float* __restrict__ g0, const float* __restrict__ b0,
    const unsigned short* __restrict__ WoT, const float* __restrict__ bo,
    unsigned short* __restrict__ O2out) {
  __shared__ __align__(16) unsigned short Aln[64 * ALD];
  __shared__ __align__(16) unsigned short Bs[64 * ALD];
  const int tid = threadIdx.x, lane = tid & 63, wid = tid >> 6;
  const int l31 = lane & 31, g2 = lane >> 5;
  const int n0 = blockIdx.x * 64, m0 = blockIdx.y * 64;
  const int wr = (wid >> 1) * 32, wc = (wid & 1) * 32;
  const int row = tid >> 2, cq = (tid & 3) * 64;

  // ---- stage B (WoT rows n0..n0+64, padded) ----
  {
    const unsigned short* src = WoT + (size_t)(n0 + row) * 256 + cq;
    #pragma unroll
    for (int j = 0; j < 8; ++j) {
      uint4 v = *(const uint4*)(src + j * 8);
      *(uint4*)&Bs[row * ALD + cq + j * 8] = v;
    }
  }

  // ---- stage A: combine + LN0 ----
  {
    const int grow = m0 + row;
    const int bb = grow >> 11, rr = grow & 2047;
    const int hh0 = cq >> 5;
    float ls0 = 0.f, ls1 = 0.f;
    #pragma unroll
    for (int s = 0; s < 4; ++s) {
      ls0 += b2f(lp[(((size_t)s * 4 + bb) * 8 + hh0) * 2048 + rr]);
      ls1 += b2f(lp[(((size_t)s * 4 + bb) * 8 + hh0 + 1) * 2048 + rr]);
    }
    const float inv0 = 1.f / ls0, inv1 = 1.f / ls1;
    const size_t base = (size_t)grow * 256 + cq;
    float sa = 0.f, sqa = 0.f;
    #pragma unroll
    for (int j = 0; j < 8; ++j) {
      U8 o0, o1, o2, o3, qv, wv;
      o0.u = *(const uint4*)(Op0 + base + j * 8);
      o1.u = *(const uint4*)(Op1 + base + j * 8);
      o2.u = *(const uint4*)(Op2 + base + j * 8);
      o3.u = *(const uint4*)(Op3 + base + j * 8);
      qv.u = *(const uint4*)(Qb + base + j * 8);
      const float inv = (j < 4) ? inv0 : inv1;
      #pragma unroll
      for (int e = 0; e < 8; ++e) {
        float xx = b2f(qv.s[e]) +
                   (b2f(o0.s[e]) + b2f(o1.s[e]) + b2f(o2.s[e]) + b2f(o3.s[e])) * inv;
        sa += xx; sqa += xx * xx;
        wv.s[e] = f2b(xx);
      }
      *(uint4*)&Aln[row * ALD + cq + j * 8] = wv.u;
    }
    sa += __shfl_xor(sa, 1);  sa += __shfl_xor(sa, 2);
    sqa += __shfl_xor(sqa, 1); sqa += __shfl_xor(sqa, 2);
    const float mean = sa * (1.f / 256.f);
    const float var = sqa * (1.f / 256.f) - mean * mean;
    const float rstd = rsqrtf(var + 1e-5f);
    #pragma unroll
    for (int j = 0; j < 8; ++j) {
      U8 wv; wv.u = *(uint4*)&Aln[row * ALD + cq + j * 8];
      float4 ga = *(const float4*)&g0[cq + j * 8];
      float4 gb = *(const float4*)&g0[cq + j * 8 + 4];
      float4 ba = *(const float4*)&b0[cq + j * 8];
      float4 bbv = *(const float4*)&b0[cq + j * 8 + 4];
      wv.s[0] = f2b((b2f(wv.s[0]) - mean) * rstd * ga.x + ba.x);
      wv.s[1] = f2b((b2f(wv.s[1]) - mean) * rstd * ga.y + ba.y);
      wv.s[2] = f2b((b2f(wv.s[2]) - mean) * rstd * ga.z + ba.z);
      wv.s[3] = f2b((b2f(wv.s[3]) - mean) * rstd * ga.w + ba.w);
      wv.s[4] = f2b((b2f(wv.s[4]) - mean) * rstd * gb.x + bbv.x);
      wv.s[5] = f2b((b2f(wv.s[5]) - mean) * rstd * gb.y + bbv.y);
      wv.s[6] = f2b((b2f(wv.s[6]) - mean) * rstd * gb.z + bbv.z);
      wv.s[7] = f2b((b2f(wv.s[7]) - mean) * rstd * gb.w + bbv.w);
      *(uint4*)&Aln[row * ALD + cq + j * 8] = wv.u;
    }
  }
  __syncthreads();

  // ---- barrier-free K-loop: 16 straight MFMAs per wave ----
  f32x16 acc = Z16;
  #pragma unroll
  for (int ks = 0; ks < 16; ++ks) {
    const int xo = ks * 32 + g2 * 16;
    bf16x8 af = *(const bf16x8*)((const char*)Aln + (wr + l31) * (ALD * 2) + xo);
    bf16x8 bf = *(const bf16x8*)((const char*)Bs + (wc + l31) * (ALD * 2) + xo);
    acc = MFMA32(af, bf, acc);
  }

  // ---- epilogue: O2 = O1n + relu(acc + bo) ----
  const int col = n0 + wc + l31;
  const float bs = bo[col];
  #pragma unroll
  for (int r = 0; r < 16; ++r) {
    const int m = m0 + wr + (r & 3) + 8 * (r >> 2) + 4 * g2;
    float v = fmaxf(acc[r] + bs, 0.f);
    v += b2f(Aln[(m - m0) * ALD + col]);
    O2out[(size_t)m * 256 + col] = f2b(v);
  }
}

// ===================== wm_fused: LN1 + Wm GEMM + relu =====================
// grid (8, 128): 64x128 tiles. A = LN1(O2) staged in LDS; B (WmT) dbuf reg-staged padded.
#define BLD 72    // B row stride shorts: 144B, 16B-aligned
__global__ __launch_bounds__(256, 2) void wm_fused(
    const unsigned short* __restrict__ O2in,
    const float* __restrict__ g1, const float* __restrict__ b1,
    const unsigned short* __restrict__ WmT, const float* __restrict__ bm,
    unsigned short* __restrict__ Mb) {
  __shared__ __align__(16) unsigned short Aln[64 * ALD];
  __shared__ __align__(16) unsigned short Bs[2 * 128 * BLD];
  const int tid = threadIdx.x, lane = tid & 63, wid = tid >> 6;
  const int l31 = lane & 31, g2 = lane >> 5;
  const int n0 = blockIdx.x * 128, m0 = blockIdx.y * 64;
  const int wr = (wid >> 1) * 32, wc = (wid & 1) * 64;

  // ---- B chunk 0 into regs ----
  const int brow = tid >> 1, bkq = (tid & 1) * 32;
  const unsigned short* srcB = WmT + (size_t)(n0 + brow) * 256 + bkq;
  uint4 breg[4];
  #pragma unroll
  for (int j = 0; j < 4; ++j) breg[j] = *(const uint4*)(srcB + j * 8);

  // ---- stage A: LN1(O2 rows) ----
  {
    const int row = tid >> 2, cq = (tid & 3) * 64;
    const int grow = m0 + row;
    const size_t base = (size_t)grow * 256 + cq;
    float sa = 0.f, sqa = 0.f;
    #pragma unroll
    for (int j = 0; j < 8; ++j) {
      U8 wv; wv.u = *(const uint4*)(O2in + base + j * 8);
      #pragma unroll
      for (int e = 0; e < 8; ++e) {
        float xx = b2f(wv.s[e]);
        sa += xx; sqa += xx * xx;
      }
      *(uint4*)&Aln[row * ALD + cq + j * 8] = wv.u;
    }
    sa += __shfl_xor(sa, 1);  sa += __shfl_xor(sa, 2);
    sqa += __shfl_xor(sqa, 1); sqa += __shfl_xor(sqa, 2);
    const float mean = sa * (1.f / 256.f);
    const float var = sqa * (1.f / 256.f) - mean * mean;
    const float rstd = rsqrtf(var + 1e-5f);
    #pragma unroll
    for (int j = 0; j < 8; ++j) {
      U8 wv; wv.u = *(uint4*)&Aln[row * ALD + cq + j * 8];
      float4 ga = *(const float4*)&g1[cq + j * 8];
      float4 gb = *(const float4*)&g1[cq + j * 8 + 4];
      float4 ba = *(const float4*)&b1[cq + j * 8];
      float4 bbv = *(const float4*)&b1[cq + j * 8 + 4];
      wv.s[0] = f2b((b2f(wv.s[0]) - mean) * rstd * ga.x + ba.x);
      wv.s[1] = f2b((b2f(wv.s[1]) - mean) * rstd * ga.y + ba.y);
      wv.s[2] = f2b((b2f(wv.s[2]) - mean) * rstd * ga.z + ba.z);
      wv.s[3] = f2b((b2f(wv.s[3]) - mean) * rstd * ga.w + ba.w);
      wv.s[4] = f2b((b2f(wv.s[4]) - mean) * rstd * gb.x + bbv.x);
      wv.s[5] = f2b((b2f(wv.s[5]) - mean) * rstd * gb.y + bbv.y);
      wv.s[6] = f2b((b2f(wv.s[6]) - mean) * rstd * gb.z + bbv.z);
      wv.s[7] = f2b((b2f(wv.s[7]) - mean) * rstd * gb.w + bbv.w);
      *(uint4*)&Aln[row * ALD + cq + j * 8] = wv.u;
    }
  }
  // write B chunk 0
  #pragma unroll
  for (int j = 0; j < 4; ++j)
    *(uint4*)&Bs[brow * BLD + bkq + j * 8] = breg[j];
  __syncthreads();

  f32x16 a0 = Z16, a1 = Z16;
  for (int t = 0; t < 4; ++t) {
    if (t < 3) {
      #pragma unroll
      for (int j = 0; j < 4; ++j)
        breg[j] = *(const uint4*)(srcB + (t + 1) * 64 + j * 8);
    }
    const char* bsc = (const char*)Bs + (t & 1) * (128 * BLD * 2);
    #pragma unroll
    for (int kc = 0; kc < 4; ++kc) {
      const int ks = t * 4 + kc;
      bf16x8 af = *(const bf16x8*)((const char*)Aln + (wr + l31) * (ALD * 2) + ks * 32 + g2 * 16);
      bf16x8 b0f = *(const bf16x8*)(bsc + (wc + l31) * (BLD * 2) + kc * 32 + g2 * 16);
      bf16x8 b1f = *(const bf16x8*)(bsc + (wc + 32 + l31) * (BLD * 2) + kc * 32 + g2 * 16);
      a0 = MFMA32(af, b0f, a0);
      a1 = MFMA32(af, b1f, a1);
    }
    if (t < 3) {
      #pragma unroll
      for (int j = 0; j < 4; ++j)
        *(uint4*)&Bs[((t + 1) & 1) * (128 * BLD) + brow * BLD + bkq + j * 8] = breg[j];
    }
    __syncthreads();
  }

  // ---- epilogue: Mb = relu(acc + bm) ----
  #pragma unroll
  for (int nb = 0; nb < 2; ++nb) {
    const f32x16& acc = nb ? a1 : a0;
    const int col = n0 + wc + nb * 32 + l31;
    const float bs = bm[col];
    #pragma unroll
    for (int r = 0; r < 16; ++r) {
      const int m = m0 + wr + (r & 3) + 8 * (r >> 2) + 4 * g2;
      Mb[(size_t)m * 1024 + col] = f2b(fmaxf(acc[r] + bs, 0.f));
    }
  }
}

// ===================== launch =====================
extern "C" void kernel_launch(void* const* d_in, const int* in_sizes, int n_in,
                              void* d_out, int out_size, void* d_ws, size_t ws_size,
                              hipStream_t stream) {
  (void)in_sizes; (void)n_in; (void)out_size; (void)ws_size;
  const float* q = (const float*)d_in[0];
  const float* x = (const float*)d_in[1];
  const float* Wq = (const float*)d_in[2];
  const float* bq = (const float*)d_in[3];
  const float* Wk = (const float*)d_in[4];
  const float* bk = (const float*)d_in[5];
  const float* Wv = (const float*)d_in[6];
  const float* bv = (const float*)d_in[7];
  const float* Wo = (const float*)d_in[8];
  const float* bo = (const float*)d_in[9];
  const float* Wm = (const float*)d_in[10];
  const float* bm = (const float*)d_in[11];
  const float* We = (const float*)d_in[12];
  const float* be = (const float*)d_in[13];
  const float* g0 = (const float*)d_in[14];
  const float* b0 = (const float*)d_in[15];
  const float* g1 = (const float*)d_in[16];
  const float* b1 = (const float*)d_in[17];
  float* out = (float*)d_out;

  uint8_t* ws = (uint8_t*)d_ws;
  // layout (extents verified, non-overlapping at each stage):
  // WoT[0,131072) WmT[131072,655360) WeT[655360,1179648) bkv[1179648,1181696)
  // WqT[1181696,1312768) WkvT[1312768,1574912)
  // qh[1576960,5771264) xh[5771264,9965568) Qb[9965568,14159872)
  // Kb[14159872,18354176) Vt[18354176,22548480) lp[22548480,23072768)
  // O2 -> over Vt [18354176,+4MB) (written by wo_fused, after attn)
  // Mb -> [1576960,18354176) 16MB (written by wm_fused; qh/xh/Qb/Kb all dead)
  unsigned short* WoT  = (unsigned short*)(ws + 0);
  unsigned short* WmT  = (unsigned short*)(ws + 131072);
  unsigned short* WeT  = (unsigned short*)(ws + 655360);
  float*          bkv  = (float*)(ws + 1179648);
  unsigned short* WqT  = (unsigned short*)(ws + 1181696);
  unsigned short* WkvT = (unsigned short*)(ws + 1312768);
  unsigned short* qh   = (unsigned short*)(ws + 1576960);
  unsigned short* xh   = (unsigned short*)(ws + 5771264);
  unsigned short* Qb   = (unsigned short*)(ws + 9965568);
  unsigned short* Kb   = (unsigned short*)(ws + 14159872);
  unsigned short* Vt   = (unsigned short*)(ws + 18354176);
  unsigned short* lp   = (unsigned short*)(ws + 22548480);
  unsigned short* Op0 = qh;
  unsigned short* Op1 = xh;
  unsigned short* Op2 = (unsigned short*)d_out;
  unsigned short* Op3 = (unsigned short*)d_out + 2097152;
  unsigned short* O2  = (unsigned short*)(ws + 18354176);
  unsigned short* Mb  = (unsigned short*)(ws + 1576960);

  prep<<<2241, 256, 0, stream>>>(q, x, qh, xh, Wq, Wk, Wv, Wo, Wm, We,
                                 WqT, WkvT, WoT, WmT, WeT, bk, bv, bkv);

  gemm_proj<<<dim3(64, 12), 256, 0, stream>>>(qh, xh, WqT, WkvT, bq, bkv, Qb, Kb, Vt);

  attn6<<<2048, 256, 0, stream>>>(Qb, Kb, Vt, Op0, Op1, Op2, Op3, lp);

  // combine + LN0 + Wo + relu + residual -> O2
  wo_fused<<<dim3(4, 128), 256, 0, stream>>>(Op0, Op1, Op2, Op3, lp, Qb,
                                             g0, b0, WoT, bo, O2);

  // LN1 + Wm + relu -> Mb
  wm_fused<<<dim3(8, 128), 256, 0, stream>>>(O2, g1, b1, WmT, bm, Mb);

  // out = Mb @ We + be + O2 (fp32)
  gemm_small<3><<<dim3(128, 4), 256, 0, stream>>>(Mb, 1024, WeT, 1024, be, O2, 256, out, 256, 1024);
}

// Round 14
// 107.736 us; speedup vs baseline: 1.6868x; 1.6868x over previous
//
#include <hip/hip_runtime.h>
#include <math.h>
#include <stdint.h>

typedef __attribute__((ext_vector_type(8))) __bf16 bf16x8;
typedef __attribute__((ext_vector_type(16))) float f32x16;

#define Z16 {0.f,0.f,0.f,0.f,0.f,0.f,0.f,0.f,0.f,0.f,0.f,0.f,0.f,0.f,0.f,0.f}

__device__ __forceinline__ unsigned short f2b(float f) {
  union { float f; uint32_t u; } v; v.f = f;
  uint32_t r = (v.u + 0x7FFFu + ((v.u >> 16) & 1u)) >> 16;
  return (unsigned short)r;
}
__device__ __forceinline__ float b2f(unsigned short u) {
  union { uint32_t u; float f; } v; v.u = ((uint32_t)u) << 16;
  return v.f;
}
__device__ __forceinline__ uint32_t pk2(float a, float b) {
  return (uint32_t)f2b(a) | ((uint32_t)f2b(b) << 16);
}
__device__ __forceinline__ uint32_t cvtpk(float lo, float hi) {
  uint32_t r;
  asm("v_cvt_pk_bf16_f32 %0, %1, %2" : "=v"(r) : "v"(lo), "v"(hi));
  return r;
}
__device__ __forceinline__ void glds16(const void* g, void* l) {
  __builtin_amdgcn_global_load_lds(
      (const __attribute__((address_space(1))) void*)g,
      (__attribute__((address_space(3))) void*)l, 16, 0, 0);
}
#define MFMA32(a, b, c) __builtin_amdgcn_mfma_f32_32x32x16_bf16(a, b, c, 0, 0, 0)

// ===================== fused preprocessing =====================
__global__ __launch_bounds__(256) void prep(
    const float* __restrict__ q, const float* __restrict__ x,
    unsigned short* __restrict__ qh, unsigned short* __restrict__ xh,
    const float* __restrict__ Wq, const float* __restrict__ Wk,
    const float* __restrict__ Wv, const float* __restrict__ Wo,
    const float* __restrict__ Wm, const float* __restrict__ We,
    unsigned short* __restrict__ WqT, unsigned short* __restrict__ WkvT,
    unsigned short* __restrict__ WoT, unsigned short* __restrict__ WmT,
    unsigned short* __restrict__ WeT,
    const float* __restrict__ bk, const float* __restrict__ bv,
    float* __restrict__ bkv) {
  __shared__ float T[64][68];
  const int bx = blockIdx.x, tid = threadIdx.x;
  if (bx < 2048) {
    const float* src = (bx < 1024) ? q : x;
    unsigned short* dst = (bx < 1024) ? qh : xh;
    const int i = (bx & 1023) * 256 + tid;
    float4 a = ((const float4*)src)[i * 2];
    float4 b = ((const float4*)src)[i * 2 + 1];
    uint4 o;
    o.x = cvtpk(a.x, a.y); o.y = cvtpk(a.z, a.w);
    o.z = cvtpk(b.x, b.y); o.w = cvtpk(b.z, b.w);
    ((uint4*)dst)[i] = o;
  } else if (bx < 2240) {
    int t = bx - 2048;
    const float* in; unsigned short* out; int ldin, ldout, kx, nx;
    if (t < 16)       { in = Wq; out = WqT;           ldin = 256;  ldout = 256;  kx = t & 3;  nx = t >> 2; }
    else if (t < 32)  { t -= 16;  in = Wk; out = WkvT;          ldin = 256;  ldout = 256;  kx = t & 3;  nx = t >> 2; }
    else if (t < 48)  { t -= 32;  in = Wv; out = WkvT + 65536;  ldin = 256;  ldout = 256;  kx = t & 3;  nx = t >> 2; }
    else if (t < 64)  { t -= 48;  in = Wo; out = WoT;           ldin = 256;  ldout = 256;  kx = t & 3;  nx = t >> 2; }
    else if (t < 128) { t -= 64;  in = Wm; out = WmT;           ldin = 1024; ldout = 256;  kx = t & 3;  nx = t >> 2; }
    else              { t -= 128; in = We; out = WeT;           ldin = 256;  ldout = 1024; kx = t & 15; nx = t >> 4; }
    const int k0 = kx * 64, n0 = nx * 64;
    const int r = tid >> 2, c16 = (tid & 3) * 16;
    #pragma unroll
    for (int i = 0; i < 4; ++i)
      *(float4*)&T[r][c16 + i * 4] =
          *(const float4*)&in[(size_t)(k0 + r) * ldin + n0 + c16 + i * 4];
    __syncthreads();
    const int n = tid >> 2, k16 = (tid & 3) * 16;
    uint32_t wb[8];
    #pragma unroll
    for (int p = 0; p < 8; ++p)
      wb[p] = cvtpk(T[k16 + 2 * p][n], T[k16 + 2 * p + 1][n]);
    uint4 o0, o1;
    o0.x = wb[0]; o0.y = wb[1]; o0.z = wb[2]; o0.w = wb[3];
    o1.x = wb[4]; o1.y = wb[5]; o1.z = wb[6]; o1.w = wb[7];
    *(uint4*)&out[(size_t)(n0 + n) * ldout + k0 + k16] = o0;
    *(uint4*)&out[(size_t)(n0 + n) * ldout + k0 + k16 + 8] = o1;
  } else {
    if (tid < 256) { bkv[tid] = bk[tid]; bkv[256 + tid] = bv[tid]; }
  }
}

// ===================== fused projections: Q + KV, 128x64 tile, BK=64, dbuf =====================
// grid (64, 12): y<4 -> Q-mode (qh@WqT -> Qb); y>=4 -> KV-mode (xh@WkvT -> Kb + Vt)
__global__ __launch_bounds__(256, 2) void gemm_proj(
    const unsigned short* __restrict__ qh, const unsigned short* __restrict__ xh,
    const unsigned short* __restrict__ WqT, const unsigned short* __restrict__ WkvT,
    const float* __restrict__ bq, const float* __restrict__ bkv,
    unsigned short* __restrict__ Qb, unsigned short* __restrict__ Kb,
    unsigned short* __restrict__ Vt) {
  __shared__ __align__(16) unsigned short As[2 * 128 * 64];
  __shared__ __align__(16) unsigned short Bs[2 * 64 * 64];
  const int tid = threadIdx.x, lane = tid & 63, wid = tid >> 6;
  const int l31 = lane & 31, g2 = lane >> 5;
  const bool qmode = blockIdx.y < 4;
  const int m0 = blockIdx.x * 128;
  const int n0 = qmode ? blockIdx.y * 64 : (blockIdx.y - 4) * 64;
  const unsigned short* A = qmode ? qh : xh;
  const unsigned short* Bt = qmode ? WqT : WkvT;
  const float* bias = qmode ? bq : bkv;

  const char* srcA[4];
  const char* srcB[2];
  #pragma unroll
  for (int p = 0; p < 4; ++p) {
    int row = p * 32 + wid * 8 + (lane >> 3);
    srcA[p] = (const char*)A + ((size_t)(m0 + row) * 256) * 2 + (lane & 7) * 16;
  }
  #pragma unroll
  for (int p = 0; p < 2; ++p) {
    int row = p * 32 + wid * 8 + (lane >> 3);
    srcB[p] = (const char*)Bt + ((size_t)(n0 + row) * 256) * 2 + (lane & 7) * 16;
  }

  f32x16 acc0 = Z16, acc1 = Z16;

  #pragma unroll
  for (int p = 0; p < 4; ++p) { glds16(srcA[p], &As[p * 2048 + wid * 512]); srcA[p] += 128; }
  #pragma unroll
  for (int p = 0; p < 2; ++p) { glds16(srcB[p], &Bs[p * 2048 + wid * 512]); srcB[p] += 128; }
  __syncthreads();

  for (int t = 0; t < 4; ++t) {
    const int cur = t & 1, nxt = cur ^ 1;
    if (t + 1 < 4) {
      #pragma unroll
      for (int p = 0; p < 4; ++p) { glds16(srcA[p], &As[nxt * 8192 + p * 2048 + wid * 512]); srcA[p] += 128; }
      #pragma unroll
      for (int p = 0; p < 2; ++p) { glds16(srcB[p], &Bs[nxt * 4096 + p * 2048 + wid * 512]); srcB[p] += 128; }
    }
    const char* as = (const char*)As + cur * 16384;
    const char* bs = (const char*)Bs + cur * 8192;
    #pragma unroll
    for (int kc = 0; kc < 4; ++kc) {
      const int xo = kc * 32 + g2 * 16;
      bf16x8 af  = *(const bf16x8*)(as + (wid * 32 + l31) * 128 + xo);
      bf16x8 b0v = *(const bf16x8*)(bs + l31 * 128 + xo);
      bf16x8 b1v = *(const bf16x8*)(bs + (32 + l31) * 128 + xo);
      acc0 = MFMA32(af, b0v, acc0);
      acc1 = MFMA32(af, b1v, acc1);
    }
    __syncthreads();
  }

  const int bb = m0 >> 11;
  #pragma unroll
  for (int nb = 0; nb < 2; ++nb) {
    const f32x16& acc = nb ? acc1 : acc0;
    const int col = n0 + nb * 32 + l31;
    const float bs = bias[col];
    if (qmode) {
      #pragma unroll
      for (int r = 0; r < 16; ++r) {
        const int m = m0 + wid * 32 + (r & 3) + 8 * (r >> 2) + 4 * g2;
        Qb[(size_t)m * 256 + col] = f2b(acc[r] + bs);
      }
    } else if (n0 < 256) {
      #pragma unroll
      for (int r = 0; r < 16; ++r) {
        const int m = m0 + wid * 32 + (r & 3) + 8 * (r >> 2) + 4 * g2;
        Kb[(size_t)m * 256 + col] = f2b(acc[r] + bs);
      }
    } else {
      const int hv = (col - 256) >> 5, dv = (col - 256) & 31;
      unsigned short* vrow = Vt + ((size_t)(bb * 8 + hv) * 32 + dv) * 2048;
      #pragma unroll
      for (int tq = 0; tq < 4; ++tq) {
        const int ks = (m0 & 2047) + wid * 32 + 8 * tq + 4 * g2;
        uint2 wv;
        wv.x = pk2(acc[4 * tq + 0] + bs, acc[4 * tq + 1] + bs);
        wv.y = pk2(acc[4 * tq + 2] + bs, acc[4 * tq + 3] + bs);
        *(uint2*)(vrow + ks) = wv;
      }
    }
  }
}

// ===================== GEMM small: 64x64 tile, BK=64, dbuf =====================
// EPI: 1 bias,relu,+res->bf16 | 3 bias,+res->f32
template <int EPI>
__global__ __launch_bounds__(256, 2) void gemm_small(
    const unsigned short* __restrict__ A, int lda,
    const unsigned short* __restrict__ Bt, int ldb,
    const float* __restrict__ bias,
    const unsigned short* __restrict__ res, int ldr,
    void* __restrict__ Cout, int ldc, int K) {
  __shared__ __align__(16) unsigned short As[2 * 64 * 64];
  __shared__ __align__(16) unsigned short Bs[2 * 64 * 64];
  const int tid = threadIdx.x, lane = tid & 63, wid = tid >> 6;
  const int l31 = lane & 31, g2 = lane >> 5;
  const int m0 = blockIdx.x * 64, n0 = blockIdx.y * 64;
  const int wr = (wid >> 1) * 32, wc = (wid & 1) * 32;

  const char* srcA[2];
  const char* srcB[2];
  #pragma unroll
  for (int p = 0; p < 2; ++p) {
    int row = p * 32 + wid * 8 + (lane >> 3);
    srcA[p] = (const char*)A + ((size_t)(m0 + row) * lda) * 2 + (lane & 7) * 16;
    srcB[p] = (const char*)Bt + ((size_t)(n0 + row) * ldb) * 2 + (lane & 7) * 16;
  }

  f32x16 acc = Z16;
  const int nt = K >> 6;

  #pragma unroll
  for (int p = 0; p < 2; ++p) {
    glds16(srcA[p], &As[p * 2048 + wid * 512]); srcA[p] += 128;
    glds16(srcB[p], &Bs[p * 2048 + wid * 512]); srcB[p] += 128;
  }
  __syncthreads();

  for (int t = 0; t < nt; ++t) {
    const int cur = t & 1, nxt = cur ^ 1;
    if (t + 1 < nt) {
      #pragma unroll
      for (int p = 0; p < 2; ++p) {
        glds16(srcA[p], &As[nxt * 4096 + p * 2048 + wid * 512]); srcA[p] += 128;
        glds16(srcB[p], &Bs[nxt * 4096 + p * 2048 + wid * 512]); srcB[p] += 128;
      }
    }
    const char* as = (const char*)As + cur * 8192;
    const char* bs = (const char*)Bs + cur * 8192;
    #pragma unroll
    for (int kc = 0; kc < 4; ++kc) {
      const int xo = kc * 32 + g2 * 16;
      bf16x8 af = *(const bf16x8*)(as + (wr + l31) * 128 + xo);
      bf16x8 bf = *(const bf16x8*)(bs + (wc + l31) * 128 + xo);
      acc = MFMA32(af, bf, acc);
    }
    __syncthreads();
  }

  const int col = n0 + wc + l31;
  const float bs = bias[col];
  #pragma unroll
  for (int r = 0; r < 16; ++r) {
    const int m = m0 + wr + (r & 3) + 8 * (r >> 2) + 4 * g2;
    float v = acc[r] + bs;
    if (EPI == 1) v = fmaxf(v, 0.f);
    if (EPI == 1 || EPI == 3) v += b2f(res[(size_t)m * ldr + col]);
    if (EPI == 3)
      ((float*)Cout)[(size_t)m * ldc + col] = v;
    else
      ((unsigned short*)Cout)[(size_t)m * ldc + col] = f2b(v);
  }
}

// ===================== GEMM 128x128: BK=64, dbuf, bias+relu->bf16 =====================
__global__ __launch_bounds__(256, 2) void gemm_relu128(
    const unsigned short* __restrict__ A, int lda,
    const unsigned short* __restrict__ Bt, int ldb,
    const float* __restrict__ bias,
    unsigned short* __restrict__ Cout, int ldc, int K) {
  __shared__ __align__(16) unsigned short As[2 * 128 * 64];
  __shared__ __align__(16) unsigned short Bs[2 * 128 * 64];
  const int tid = threadIdx.x, lane = tid & 63, wid = tid >> 6;
  const int l31 = lane & 31, g2 = lane >> 5;
  const int m0 = blockIdx.x * 128, n0 = blockIdx.y * 128;
  const int wr = (wid >> 1) * 64, wc = (wid & 1) * 64;

  const char* srcA[4];
  const char* srcB[4];
  #pragma unroll
  for (int p = 0; p < 4; ++p) {
    int row = p * 32 + wid * 8 + (lane >> 3);
    srcA[p] = (const char*)A + ((size_t)(m0 + row) * lda) * 2 + (lane & 7) * 16;
    srcB[p] = (const char*)Bt + ((size_t)(n0 + row) * ldb) * 2 + (lane & 7) * 16;
  }

  f32x16 a00 = Z16, a01 = Z16, a10 = Z16, a11 = Z16;
  const int nt = K >> 6;

  #pragma unroll
  for (int p = 0; p < 4; ++p) {
    glds16(srcA[p], &As[p * 2048 + wid * 512]); srcA[p] += 128;
    glds16(srcB[p], &Bs[p * 2048 + wid * 512]); srcB[p] += 128;
  }
  __syncthreads();

  for (int t = 0; t < nt; ++t) {
    const int cur = t & 1, nxt = cur ^ 1;
    if (t + 1 < nt) {
      #pragma unroll
      for (int p = 0; p < 4; ++p) {
        glds16(srcA[p], &As[nxt * 8192 + p * 2048 + wid * 512]); srcA[p] += 128;
        glds16(srcB[p], &Bs[nxt * 8192 + p * 2048 + wid * 512]); srcB[p] += 128;
      }
    }
    const char* as = (const char*)As + cur * 16384;
    const char* bs = (const char*)Bs + cur * 16384;
    #pragma unroll
    for (int kc = 0; kc < 4; ++kc) {
      const int xo = kc * 32 + g2 * 16;
      bf16x8 af0 = *(const bf16x8*)(as + (wr + l31) * 128 + xo);
      bf16x8 af1 = *(const bf16x8*)(as + (wr + 32 + l31) * 128 + xo);
      bf16x8 bf0 = *(const bf16x8*)(bs + (wc + l31) * 128 + xo);
      bf16x8 bf1 = *(const bf16x8*)(bs + (wc + 32 + l31) * 128 + xo);
      a00 = MFMA32(af0, bf0, a00);
      a01 = MFMA32(af0, bf1, a01);
      a10 = MFMA32(af1, bf0, a10);
      a11 = MFMA32(af1, bf1, a11);
    }
    __syncthreads();
  }

  #pragma unroll
  for (int mf = 0; mf < 2; ++mf)
    #pragma unroll
    for (int nb = 0; nb < 2; ++nb) {
      const f32x16& acc = mf ? (nb ? a11 : a10) : (nb ? a01 : a00);
      const int col = n0 + wc + nb * 32 + l31;
      const float bs = bias[col];
      #pragma unroll
      for (int r = 0; r < 16; ++r) {
        const int m = m0 + wr + mf * 32 + (r & 3) + 8 * (r >> 2) + 4 * g2;
        Cout[(size_t)m * ldc + col] = f2b(fmaxf(acc[r] + bs, 0.f));
      }
    }
}

// ===================== attention v6: kv-split x4, KVBLK=128, no-max softmax =====================
// 2048 blocks (XCD-swizzled); 4 waves; wave owns 32 q-rows; block does 512 keys.
#define KLD 40
#define VLD2 136
__global__ __launch_bounds__(256, 4) void attn6(
    const unsigned short* __restrict__ Qg,
    const unsigned short* __restrict__ Kb,
    const unsigned short* __restrict__ Vt,
    unsigned short* __restrict__ Op0, unsigned short* __restrict__ Op1,
    unsigned short* __restrict__ Op2, unsigned short* __restrict__ Op3,
    unsigned short* __restrict__ lp) {
  __shared__ __align__(16) unsigned short Ks[128 * KLD];
  __shared__ __align__(16) unsigned short Vs[32 * VLD2];
  const int tid = threadIdx.x, lane = tid & 63, wid = tid >> 6;
  const int l31 = lane & 31, g2 = lane >> 5;
  const int w = (blockIdx.x >> 3) + (blockIdx.x & 7) * 256;
  const int b = w >> 9, h = (w >> 6) & 7, kv = (w >> 4) & 3, qt = w & 15;
  const int row0 = b * 2048 + qt * 128;
  const int qrow = row0 + wid * 32 + l31;
  const int kt0 = kv * 512;

  const float SCL2 = 0.17677669529663687f * 1.4426950408889634f;
  bf16x8 qf0, qf1;
  {
    const unsigned short* qp = Qg + (size_t)qrow * 256 + h * 32 + g2 * 8;
    #pragma unroll
    for (int dc = 0; dc < 2; ++dc) {
      ushort4 r0 = *(const ushort4*)(qp + dc * 16);
      ushort4 r1 = *(const ushort4*)(qp + dc * 16 + 4);
      union { unsigned short s[8]; bf16x8 v; } u;
      u.s[0] = f2b(b2f(r0.x) * SCL2); u.s[1] = f2b(b2f(r0.y) * SCL2);
      u.s[2] = f2b(b2f(r0.z) * SCL2); u.s[3] = f2b(b2f(r0.w) * SCL2);
      u.s[4] = f2b(b2f(r1.x) * SCL2); u.s[5] = f2b(b2f(r1.y) * SCL2);
      u.s[6] = f2b(b2f(r1.z) * SCL2); u.s[7] = f2b(b2f(r1.w) * SCL2);
      if (dc == 0) qf0 = u.v; else qf1 = u.v;
    }
  }

  const int ksr = tid >> 2, ksc = (tid & 3) * 8;
  const unsigned short* srcK = Kb + (size_t)(b * 2048 + kt0 + ksr) * 256 + h * 32 + ksc;
  const int vd = tid >> 3, vk = (tid & 7) * 8;
  const unsigned short* srcV = Vt + ((size_t)((b * 8 + h) * 32 + vd)) * 2048 + kt0 + vk;

  uint4 kreg0 = *(const uint4*)srcK;
  uint4 kreg1 = *(const uint4*)(srcK + 64 * 256);
  uint4 vreg0 = *(const uint4*)srcV;
  uint4 vreg1 = *(const uint4*)(srcV + 64);

  f32x16 oacc = Z16;
  float lr0 = 0.f, lr1 = 0.f;

  for (int kt = 0; kt < 512; kt += 128) {
    *(uint4*)&Ks[ksr * KLD + ksc] = kreg0;
    *(uint4*)&Ks[(64 + ksr) * KLD + ksc] = kreg1;
    *(uint4*)&Vs[vd * VLD2 + vk] = vreg0;
    *(uint4*)&Vs[vd * VLD2 + 64 + vk] = vreg1;
    __syncthreads();

    if (kt + 128 < 512) {
      srcK += 128 * 256;
      kreg0 = *(const uint4*)srcK;
      kreg1 = *(const uint4*)(srcK + 64 * 256);
      srcV += 128;
      vreg0 = *(const uint4*)srcV;
      vreg1 = *(const uint4*)(srcV + 64);
    }

    #pragma unroll
    for (int st = 0; st < 2; ++st) {
      const int kb0 = st * 64;
      f32x16 p0 = Z16, p1 = Z16;
      {
        bf16x8 k00 = *(const bf16x8*)&Ks[(kb0 + l31) * KLD + g2 * 8];
        bf16x8 k01 = *(const bf16x8*)&Ks[(kb0 + l31) * KLD + 16 + g2 * 8];
        bf16x8 k10 = *(const bf16x8*)&Ks[(kb0 + 32 + l31) * KLD + g2 * 8];
        bf16x8 k11 = *(const bf16x8*)&Ks[(kb0 + 32 + l31) * KLD + 16 + g2 * 8];
        p0 = MFMA32(k00, qf0, p0);
        p0 = MFMA32(k01, qf1, p0);
        p1 = MFMA32(k10, qf0, p1);
        p1 = MFMA32(k11, qf1, p1);
      }

      float s0 = 0.f, s1 = 0.f;
      #pragma unroll
      for (int i = 0; i < 16; ++i) { p0[i] = __builtin_amdgcn_exp2f(p0[i]); s0 += p0[i]; }
      #pragma unroll
      for (int i = 0; i < 16; ++i) { p1[i] = __builtin_amdgcn_exp2f(p1[i]); s1 += p1[i]; }
      lr0 += s0; lr1 += s1;

      #pragma unroll
      for (int rb = 0; rb < 2; ++rb) {
        const f32x16& pp = rb ? p1 : p0;
        #pragma unroll
        for (int c = 0; c < 2; ++c) {
          uint32_t A0 = cvtpk(pp[8 * c + 0], pp[8 * c + 1]);
          uint32_t A1 = cvtpk(pp[8 * c + 2], pp[8 * c + 3]);
          uint32_t B0 = cvtpk(pp[8 * c + 4], pp[8 * c + 5]);
          uint32_t B1 = cvtpk(pp[8 * c + 6], pp[8 * c + 7]);
          uint32_t pA0 = (uint32_t)__shfl_xor((int)A0, 32);
          uint32_t pB0 = (uint32_t)__shfl_xor((int)B0, 32);
          uint32_t pA1 = (uint32_t)__shfl_xor((int)A1, 32);
          uint32_t pB1 = (uint32_t)__shfl_xor((int)B1, 32);
          union { uint32_t u[4]; bf16x8 v; } fr;
          fr.u[0] = g2 ? pB0 : A0;
          fr.u[1] = g2 ? pB1 : A1;
          fr.u[2] = g2 ? B0 : pA0;
          fr.u[3] = g2 ? B1 : pA1;
          bf16x8 vf = *(const bf16x8*)&Vs[l31 * VLD2 + kb0 + rb * 32 + c * 16 + g2 * 8];
          oacc = MFMA32(vf, fr.v, oacc);
        }
      }
    }
    __syncthreads();
  }

  float lrun = lr0 + lr1;
  lrun += __shfl_xor(lrun, 32);
  unsigned short* op =
      (kv == 0 ? Op0 : kv == 1 ? Op1 : kv == 2 ? Op2 : Op3) +
      (size_t)qrow * 256 + h * 32;
  #pragma unroll
  for (int j = 0; j < 4; ++j) {
    uint2 wv;
    wv.x = cvtpk(oacc[4 * j + 0], oacc[4 * j + 1]);
    wv.y = cvtpk(oacc[4 * j + 2], oacc[4 * j + 3]);
    *(uint2*)(op + 8 * j + 4 * g2) = wv;
  }
  if (g2 == 0)
    lp[(((size_t)kv * 4 + b) * 8 + h) * 2048 + (qt * 128 + wid * 32 + l31)] = f2b(lrun);
}

// ===================== combine + Q residual + LN0 =====================
__global__ __launch_bounds__(256) void combine_ln0(
    const unsigned short* __restrict__ Op0, const unsigned short* __restrict__ Op1,
    const unsigned short* __restrict__ Op2, const unsigned short* __restrict__ Op3,
    const unsigned short* __restrict__ lp,
    const unsigned short* __restrict__ Qb,
    const float* __restrict__ gw, const float* __restrict__ bw,
    unsigned short* __restrict__ O1n) {
  const int wid = threadIdx.x >> 6, lane = threadIdx.x & 63;
  const int row = blockIdx.x * 4 + wid;
  const int b = row >> 11, rr = row & 2047, hh = lane >> 3;
  float lsum = 0.f;
  #pragma unroll
  for (int s = 0; s < 4; ++s)
    lsum += b2f(lp[(((size_t)s * 4 + b) * 8 + hh) * 2048 + rr]);
  const float inv = 1.f / lsum;
  const size_t off = (size_t)row * 256 + lane * 4;
  ushort4 oa = *(const ushort4*)(Op0 + off);
  ushort4 ob = *(const ushort4*)(Op1 + off);
  ushort4 oc = *(const ushort4*)(Op2 + off);
  ushort4 od = *(const ushort4*)(Op3 + off);
  ushort4 qv = *(const ushort4*)(Qb + off);
  float x0 = b2f(qv.x) + (b2f(oa.x) + b2f(ob.x) + b2f(oc.x) + b2f(od.x)) * inv;
  float x1 = b2f(qv.y) + (b2f(oa.y) + b2f(ob.y) + b2f(oc.y) + b2f(od.y)) * inv;
  float x2 = b2f(qv.z) + (b2f(oa.z) + b2f(ob.z) + b2f(oc.z) + b2f(od.z)) * inv;
  float x3 = b2f(qv.w) + (b2f(oa.w) + b2f(ob.w) + b2f(oc.w) + b2f(od.w)) * inv;
  float s = x0 + x1 + x2 + x3;
  float sq = x0 * x0 + x1 * x1 + x2 * x2 + x3 * x3;
  #pragma unroll
  for (int off2 = 32; off2 >= 1; off2 >>= 1) {
    s += __shfl_xor(s, off2);
    sq += __shfl_xor(sq, off2);
  }
  const float mean = s * (1.f / 256.f);
  const float var = sq * (1.f / 256.f) - mean * mean;
  const float rstd = rsqrtf(var + 1e-5f);
  float4 gv = *(const float4*)&gw[lane * 4];
  float4 bv = *(const float4*)&bw[lane * 4];
  ushort4 o;
  o.x = f2b((x0 - mean) * rstd * gv.x + bv.x);
  o.y = f2b((x1 - mean) * rstd * gv.y + bv.y);
  o.z = f2b((x2 - mean) * rstd * gv.z + bv.z);
  o.w = f2b((x3 - mean) * rstd * gv.w + bv.w);
  *(ushort4*)(O1n + off) = o;
}

// ===================== LayerNorm (bf16 in/out) =====================
__global__ __launch_bounds__(256) void ln_k(
    const unsigned short* __restrict__ X, const float* __restrict__ gw,
    const float* __restrict__ bw, unsigned short* __restrict__ Y) {
  const int wid = threadIdx.x >> 6, lane = threadIdx.x & 63;
  const int row = blockIdx.x * 4 + wid;
  ushort4 xv = *(const ushort4*)(X + (size_t)row * 256 + lane * 4);
  float x0 = b2f(xv.x), x1 = b2f(xv.y), x2 = b2f(xv.z), x3 = b2f(xv.w);
  float s = x0 + x1 + x2 + x3;
  float sq = x0 * x0 + x1 * x1 + x2 * x2 + x3 * x3;
  #pragma unroll
  for (int off = 32; off >= 1; off >>= 1) {
    s += __shfl_xor(s, off);
    sq += __shfl_xor(sq, off);
  }
  const float mean = s * (1.f / 256.f);
  const float var = sq * (1.f / 256.f) - mean * mean;
  const float rstd = rsqrtf(var + 1e-5f);
  float4 gv = *(const float4*)&gw[lane * 4];
  float4 bv = *(const float4*)&bw[lane * 4];
  ushort4 o;
  o.x = f2b((x0 - mean) * rstd * gv.x + bv.x);
  o.y = f2b((x1 - mean) * rstd * gv.y + bv.y);
  o.z = f2b((x2 - mean) * rstd * gv.z + bv.z);
  o.w = f2b((x3 - mean) * rstd * gv.w + bv.w);
  *(ushort4*)(Y + (size_t)row * 256 + lane * 4) = o;
}

// ===================== launch =====================
extern "C" void kernel_launch(void* const* d_in, const int* in_sizes, int n_in,
                              void* d_out, int out_size, void* d_ws, size_t ws_size,
                              hipStream_t stream) {
  (void)in_sizes; (void)n_in; (void)out_size; (void)ws_size;
  const float* q = (const float*)d_in[0];
  const float* x = (const float*)d_in[1];
  const float* Wq = (const float*)d_in[2];
  const float* bq = (const float*)d_in[3];
  const float* Wk = (const float*)d_in[4];
  const float* bk = (const float*)d_in[5];
  const float* Wv = (const float*)d_in[6];
  const float* bv = (const float*)d_in[7];
  const float* Wo = (const float*)d_in[8];
  const float* bo = (const float*)d_in[9];
  const float* Wm = (const float*)d_in[10];
  const float* bm = (const float*)d_in[11];
  const float* We = (const float*)d_in[12];
  const float* be = (const float*)d_in[13];
  const float* g0 = (const float*)d_in[14];
  const float* b0 = (const float*)d_in[15];
  const float* g1 = (const float*)d_in[16];
  const float* b1 = (const float*)d_in[17];
  float* out = (float*)d_out;

  uint8_t* ws = (uint8_t*)d_ws;
  // non-overlapping layout (extents verified):
  // WoT[0,131072) WmT[131072,655360) WeT[655360,1179648) bkv[1179648,1181696)
  // WqT[1181696,1312768) WkvT[1312768,1574912)
  // qh[1576960,5771264) xh[5771264,9965568) Qb[9965568,14159872)
  // Kb[14159872,18354176) Vt[18354176,22548480) lp[22548480,23072768)
  unsigned short* WoT  = (unsigned short*)(ws + 0);
  unsigned short* WmT  = (unsigned short*)(ws + 131072);
  unsigned short* WeT  = (unsigned short*)(ws + 655360);
  float*          bkv  = (float*)(ws + 1179648);
  unsigned short* WqT  = (unsigned short*)(ws + 1181696);
  unsigned short* WkvT = (unsigned short*)(ws + 1312768);
  unsigned short* qh   = (unsigned short*)(ws + 1576960);
  unsigned short* xh   = (unsigned short*)(ws + 5771264);
  unsigned short* Qb   = (unsigned short*)(ws + 9965568);
  unsigned short* Kb   = (unsigned short*)(ws + 14159872);
  unsigned short* Vt   = (unsigned short*)(ws + 18354176);
  unsigned short* lp   = (unsigned short*)(ws + 22548480);
  // attention bf16 partials: overlay dead regions + d_out scratch
  unsigned short* Op0 = qh;                                // over qh (dead after proj)
  unsigned short* Op1 = xh;                                // over xh (dead after proj)
  unsigned short* Op2 = (unsigned short*)d_out;            // d_out first 4 MB
  unsigned short* Op3 = (unsigned short*)d_out + 2097152;  // d_out second 4 MB
  // phase 2 reuse
  unsigned short* O1n = (unsigned short*)(ws + 14159872);  // over Kb (dead after attn)
  unsigned short* O2  = (unsigned short*)(ws + 1576960);   // over Op0 (dead after combine)
  unsigned short* O2n = (unsigned short*)(ws + 5771264);   // over Op1
  unsigned short* Mb  = (unsigned short*)(ws + 14159872);  // 16 MB, ends 30937088

  prep<<<2241, 256, 0, stream>>>(q, x, qh, xh, Wq, Wk, Wv, Wo, Wm, We,
                                 WqT, WkvT, WoT, WmT, WeT, bk, bv, bkv);

  // fused Q + KV projections
  gemm_proj<<<dim3(64, 12), 256, 0, stream>>>(qh, xh, WqT, WkvT, bq, bkv, Qb, Kb, Vt);

  // attention (kv-split x4, KVBLK=128) -> bf16 partials
  attn6<<<2048, 256, 0, stream>>>(Qb, Kb, Vt, Op0, Op1, Op2, Op3, lp);
  // combine + Q residual + LN0 -> O1n
  combine_ln0<<<2048, 256, 0, stream>>>(Op0, Op1, Op2, Op3, lp, Qb, g0, b0, O1n);

  // O2 = O1n + relu(O1n @ Wo + bo)
  gemm_small<1><<<dim3(128, 4), 256, 0, stream>>>(O1n, 256, WoT, 256, bo, O1n, 256, O2, 256, 256);
  // LN1
  ln_k<<<2048, 256, 0, stream>>>(O2, g1, b1, O2n);

  // MLP: M = relu(O2n @ Wm + bm), 128x128 tile
  gemm_relu128<<<dim3(64, 8), 256, 0, stream>>>(O2n, 256, WmT, 256, bm, Mb, 1024, 256);
  // out = M @ We + be + O2 (fp32)
  gemm_small<3><<<dim3(128, 4), 256, 0, stream>>>(Mb, 1024, WeT, 1024, be, O2, 256, out, 256, 1024);
}